// Round 1
// baseline (268.557 us; speedup 1.0000x reference)
//
#include <hip/hip_runtime.h>
#include <math.h>

// SpectralConv1d: y = irfft( einsum('bim,iom->bom', rfft(x)[:,:,:16], W) )
// B=64, Cin=64, Cout=64, MODES=16, RES=8192.
// Only 16 modes kept -> direct 16-mode DFT/synthesis with n = a + 512*b
// factorization (inner 16-pt DFT has compile-time constant twiddles).
// ws usage: X [4096][16][2] f32 (512 KB) + C [4096][16][2] f32 (512 KB) = 1 MB.

#define B_     64
#define CIN_   64
#define COUT_  64
#define MODES_ 16
#define RES_   8192
#define NA     512   // RES_/16

__device__ static constexpr float COS16[16] = {
     1.0f,  0.92387953251128674f,  0.70710678118654752f,  0.38268343236508977f,
     0.0f, -0.38268343236508977f, -0.70710678118654752f, -0.92387953251128674f,
    -1.0f, -0.92387953251128674f, -0.70710678118654752f, -0.38268343236508977f,
     0.0f,  0.38268343236508977f,  0.70710678118654752f,  0.92387953251128674f
};
__device__ static constexpr float SIN16[16] = {
     0.0f,  0.38268343236508977f,  0.70710678118654752f,  0.92387953251128674f,
     1.0f,  0.92387953251128674f,  0.70710678118654752f,  0.38268343236508977f,
     0.0f, -0.38268343236508977f, -0.70710678118654752f, -0.92387953251128674f,
    -1.0f, -0.92387953251128674f, -0.70710678118654752f, -0.38268343236508977f
};

#define TWO_PI_OVER_RES 7.66990393942820428e-4f  // 2*pi/8192

// ---------------- Stage A: X[row,k] = sum_n x[row,n] e^{-2pi i k n / 8192}, k=0..15
// row = b*CIN_ + i.  One block per row, 256 threads.
__global__ __launch_bounds__(256) void kA(const float* __restrict__ x,
                                          float* __restrict__ X) {
    __shared__ float T[NA][20];      // [a][2*k'+{re,im}], k'=0..8  (40 KB)
    __shared__ float P[16][16][2];   // per-mode partials
    const int row = blockIdx.x;
    const int tid = threadIdx.x;
    const float* __restrict__ xr = x + (size_t)row * RES_;

    // Phase 1: inner 16-point real DFT over b (stride-512 samples), constant twiddles.
    for (int a = tid; a < NA; a += 256) {
        float xv[16];
#pragma unroll
        for (int b = 0; b < 16; ++b) xv[b] = xr[a + NA * b];
#pragma unroll
        for (int k = 0; k <= 8; ++k) {
            float sr = 0.f, si = 0.f;
#pragma unroll
            for (int b = 0; b < 16; ++b) {
                sr = fmaf(xv[b],  COS16[(k * b) & 15], sr);
                si = fmaf(xv[b], -SIN16[(k * b) & 15], si);
            }
            T[a][2 * k]     = sr;
            T[a][2 * k + 1] = si;
        }
    }
    __syncthreads();

    // Phase 2: X[k] = sum_a e^{-2pi i k a/8192} T[a][k]  (Hermitian: k>8 -> conj T[16-k])
    const int k = tid & 15;
    const int c = tid >> 4;                 // 0..15 a-residues
    const int kp = (k <= 8) ? k : 16 - k;
    const float sgn = (k <= 8) ? 1.f : -1.f;
    float accr = 0.f, acci = 0.f;
    for (int j = 0; j < 32; ++j) {
        const int a = c + 16 * j;
        const int m = (k * a) & (RES_ - 1);
        float sv, cv;
        __sincosf((float)m * TWO_PI_OVER_RES, &sv, &cv);
        const float tr = T[a][2 * kp];
        const float ti = sgn * T[a][2 * kp + 1];
        accr += cv * tr + sv * ti;          // (cos - i sin)(tr + i ti)
        acci += cv * ti - sv * tr;
    }
    P[k][c][0] = accr;
    P[k][c][1] = acci;
    __syncthreads();
    if (tid < 16) {
        float xre = 0.f, xim = 0.f;
#pragma unroll
        for (int c2 = 0; c2 < 16; ++c2) { xre += P[tid][c2][0]; xim += P[tid][c2][1]; }
        X[row * 32 + 2 * tid]     = xre;
        X[row * 32 + 2 * tid + 1] = xim;
    }
}

// ---------------- Stage B: C[b,o,k] = sum_i X[b,i,k] * (wr + i wi)[i,o,k]
// One block per b, 256 threads = 16 k x 16 o-groups (4 o each).
__global__ __launch_bounds__(256) void kB(const float* __restrict__ X,
                                          const float* __restrict__ wr,
                                          const float* __restrict__ wi,
                                          float* __restrict__ C) {
    __shared__ float Xs[CIN_][32];   // 8 KB
    const int b = blockIdx.x;
    const int tid = threadIdx.x;
    const float* __restrict__ Xb = X + b * CIN_ * 32;
    for (int t = tid; t < CIN_ * 32; t += 256) ((float*)Xs)[t] = Xb[t];
    __syncthreads();

    const int k  = tid & 15;
    const int og = tid >> 4;         // 0..15
    float acc[4][2] = {};
    for (int i = 0; i < CIN_; ++i) {
        const float xre = Xs[i][2 * k];
        const float xim = Xs[i][2 * k + 1];
#pragma unroll
        for (int m = 0; m < 4; ++m) {
            const int o = og * 4 + m;
            const float wrv = wr[(i * COUT_ + o) * MODES_ + k];
            const float wiv = wi[(i * COUT_ + o) * MODES_ + k];
            acc[m][0] += xre * wrv - xim * wiv;
            acc[m][1] += xre * wiv + xim * wrv;
        }
    }
#pragma unroll
    for (int m = 0; m < 4; ++m) {
        const int o = og * 4 + m;
        C[((b * COUT_ + o) * MODES_ + k) * 2 + 0] = acc[m][0];
        C[((b * COUT_ + o) * MODES_ + k) * 2 + 1] = acc[m][1];
    }
}

// ---------------- Stage C: y[row, a+512b] = sum_k g_k Re(C_k e^{2pi i k (a+512b)/8192})
// g_0 = 1/N, g_k = 2/N.  One block per row (= b*COUT_+o), 256 threads.
__global__ __launch_bounds__(256) void kC(const float* __restrict__ C,
                                          float* __restrict__ y) {
    __shared__ float Cs[32];
    const int row = blockIdx.x;
    const int tid = threadIdx.x;
    if (tid < 32) Cs[tid] = C[row * 32 + tid];
    __syncthreads();
    float* __restrict__ yr = y + (size_t)row * RES_;

#pragma unroll
    for (int rep = 0; rep < 2; ++rep) {
        const int a = tid + rep * 256;
        float Dre[16], Dim[16];
#pragma unroll
        for (int k = 0; k < 16; ++k) {
            const int m = (k * a) & (RES_ - 1);
            float sv, cv;
            __sincosf((float)m * TWO_PI_OVER_RES, &sv, &cv);
            const float cr = Cs[2 * k], ci = Cs[2 * k + 1];
            const float g = (k == 0) ? (1.0f / RES_) : (2.0f / RES_);
            Dre[k] = g * (cr * cv - ci * sv);   // C_k * e^{+i theta}
            Dim[k] = g * (cr * sv + ci * cv);
        }
#pragma unroll
        for (int bb = 0; bb < 16; ++bb) {
            float v = 0.f;
#pragma unroll
            for (int k = 0; k < 16; ++k) {
                v = fmaf(Dre[k],  COS16[(k * bb) & 15], v);
                v = fmaf(Dim[k], -SIN16[(k * bb) & 15], v);
            }
            yr[a + NA * bb] = v;
        }
    }
}

extern "C" void kernel_launch(void* const* d_in, const int* in_sizes, int n_in,
                              void* d_out, int out_size, void* d_ws, size_t ws_size,
                              hipStream_t stream) {
    const float* x  = (const float*)d_in[0];
    const float* wr = (const float*)d_in[1];
    const float* wi = (const float*)d_in[2];
    float* out = (float*)d_out;

    float* X = (float*)d_ws;                      // [4096][32] = 512 KB
    float* C = X + (size_t)B_ * CIN_ * 32;        // [4096][32] = 512 KB

    kA<<<dim3(B_ * CIN_), dim3(256), 0, stream>>>(x, X);
    kB<<<dim3(B_), dim3(256), 0, stream>>>(X, wr, wi, C);
    kC<<<dim3(B_ * COUT_), dim3(256), 0, stream>>>(C, out);
}

// Round 2
// 240.458 us; speedup vs baseline: 1.1169x; 1.1169x over previous
//
#include <hip/hip_runtime.h>
#include <math.h>

// SpectralConv1d: y = irfft( einsum('bim,iom->bom', rfft(x)[:,:,:16], W) )
// B=64, Cin=64, Cout=64, MODES=16, RES=8192.
// n = a + 512*b factorization: inner 16-pt real DFT (constant twiddles,
// even/odd folded), outer 512-term twiddled sum via rotation recurrence.
// kC fuses the Cin-contraction (tiny) with the 16-mode synthesis.
// ws: X [4096][32] f32 = 512 KB.

#define B_     64
#define CIN_   64
#define COUT_  64
#define MODES_ 16
#define RES_   8192
#define NA     512          // RES_/16
#define PITCH  522          // LDS row pitch for Ts (even -> 8B-aligned float2)

__device__ static constexpr float COS16[16] = {
     1.0f,  0.92387953251128674f,  0.70710678118654752f,  0.38268343236508977f,
     0.0f, -0.38268343236508977f, -0.70710678118654752f, -0.92387953251128674f,
    -1.0f, -0.92387953251128674f, -0.70710678118654752f, -0.38268343236508977f,
     0.0f,  0.38268343236508977f,  0.70710678118654752f,  0.92387953251128674f
};
__device__ static constexpr float SIN16[16] = {
     0.0f,  0.38268343236508977f,  0.70710678118654752f,  0.92387953251128674f,
     1.0f,  0.92387953251128674f,  0.70710678118654752f,  0.38268343236508977f,
     0.0f, -0.38268343236508977f, -0.70710678118654752f, -0.92387953251128674f,
    -1.0f, -0.92387953251128674f, -0.70710678118654752f, -0.38268343236508977f
};

#define W8192 7.66990393942820428e-4f   // 2*pi/8192

// ---------------- Stage A: X[row,k] = sum_n x[row,n] e^{-2pi i k n/8192}, k=0..15
// One block per row (4096 blocks), 256 threads.
__global__ __launch_bounds__(256) void kA(const float* __restrict__ x,
                                          float* __restrict__ X) {
    __shared__ float Ts[18 * PITCH];     // [kslot][a]: kslot=2k(re),2k+1(im), k=0..8
    __shared__ float P[16][17][2];
    const int row = blockIdx.x;
    const int tid = threadIdx.x;
    const float* __restrict__ xr = x + (size_t)row * RES_;

    // Phase 1: 16-pt real DFT over b at a = 2*tid, 2*tid+1 (float2 loads).
    float2 m[16];
#pragma unroll
    for (int b = 0; b < 16; ++b)
        m[b] = *(const float2*)(xr + 2 * tid + NA * b);

    float2 x0 = m[0], x8 = m[8];
    float2 ev[8], ov[8];                 // folds: ev[b]=m[b]+m[16-b], ov[b]=m[b]-m[16-b]
#pragma unroll
    for (int b = 1; b <= 7; ++b) {
        ev[b].x = m[b].x + m[16 - b].x;  ev[b].y = m[b].y + m[16 - b].y;
        ov[b].x = m[b].x - m[16 - b].x;  ov[b].y = m[b].y - m[16 - b].y;
    }
#pragma unroll
    for (int k = 0; k <= 8; ++k) {
        float sr0 = (k & 1) ? (x0.x - x8.x) : (x0.x + x8.x);
        float sr1 = (k & 1) ? (x0.y - x8.y) : (x0.y + x8.y);
        float si0 = 0.f, si1 = 0.f;
#pragma unroll
        for (int b = 1; b <= 7; ++b) {
            const float cc = COS16[(k * b) & 15];
            const float ss = SIN16[(k * b) & 15];
            sr0 = fmaf(ev[b].x, cc, sr0);
            sr1 = fmaf(ev[b].y, cc, sr1);
            si0 = fmaf(ov[b].x, -ss, si0);
            si1 = fmaf(ov[b].y, -ss, si1);
        }
        *(float2*)&Ts[(2 * k) * PITCH + 2 * tid]     = make_float2(sr0, sr1);
        *(float2*)&Ts[(2 * k + 1) * PITCH + 2 * tid] = make_float2(si0, si1);
    }
    __syncthreads();

    // Phase 2: X[k] = sum_a e^{-2pi i k a/8192} t_k[a]; Hermitian t: k>8 -> conj t[16-k].
    // Twiddle via rotation recurrence: base a=c, step a+=16.
    const int k  = tid & 15;
    const int c  = tid >> 4;             // a-residue 0..15
    const int kp = (k <= 8) ? k : 16 - k;
    const float sgn = (k <= 8) ? 1.f : -1.f;
    float sA, cA, sB, cB;
    __sincosf((float)(k * c)  * W8192, &sA, &cA);
    __sincosf((float)(k * 16) * W8192, &sB, &cB);
    float wre = cA, wim = -sA;           // e^{-2pi i k c/8192}
    const float sre = cB, sim = -sB;     // e^{-2pi i k*16/8192}
    float accr = 0.f, acci = 0.f;
    const float* __restrict__ Tr = &Ts[(2 * kp) * PITCH + c];
    const float* __restrict__ Ti = &Ts[(2 * kp + 1) * PITCH + c];
#pragma unroll 8
    for (int j = 0; j < 32; ++j) {
        const float tr = Tr[16 * j];
        const float ti = sgn * Ti[16 * j];
        accr = fmaf(wre, tr, fmaf(-wim, ti, accr));
        acci = fmaf(wre, ti, fmaf( wim, tr, acci));
        const float nre = fmaf(wre, sre, -wim * sim);
        wim = fmaf(wre, sim, wim * sre);
        wre = nre;
    }
    P[k][c][0] = accr;
    P[k][c][1] = acci;
    __syncthreads();
    if (tid < 16) {
        float xre = 0.f, xim = 0.f;
#pragma unroll
        for (int c2 = 0; c2 < 16; ++c2) { xre += P[tid][c2][0]; xim += P[tid][c2][1]; }
        *(float2*)&X[row * 32 + 2 * tid] = make_float2(xre, xim);
    }
}

// ---------------- Stage C (fused B+C): per block (b,o):
//   C_k = g_k * sum_i X[b,i,k] * W[i,o,k]   (g_0=1/N, g_k=2/N)
//   y[a+512*bb] = sum_k Re( C_k e^{2pi i k a/8192} e^{i pi k bb/8} )
// One block per output row (4096 blocks), 256 threads.
__global__ __launch_bounds__(256) void kC(const float* __restrict__ X,
                                          const float* __restrict__ wr,
                                          const float* __restrict__ wi,
                                          float* __restrict__ y) {
    __shared__ float Xs[CIN_ * 32];      // 8 KB
    __shared__ float Ps[16][17][2];
    __shared__ float Csh[32];
    const int row = blockIdx.x;          // b*COUT_ + o
    const int b = row >> 6, o = row & 63;
    const int tid = threadIdx.x;

    // load X[b,:,:] into LDS (float4)
    const float4* __restrict__ Xb4 = (const float4*)(X + (size_t)b * CIN_ * 32);
    for (int t = tid; t < CIN_ * 8; t += 256)
        ((float4*)Xs)[t] = Xb4[t];
    __syncthreads();

    // contraction over Cin: 16 partials per k
    {
        const int k = tid & 15, p = tid >> 4;
        float pr = 0.f, pi = 0.f;
#pragma unroll
        for (int mI = 0; mI < 4; ++mI) {
            const int i = 4 * p + mI;
            const float xre = Xs[i * 32 + 2 * k];
            const float xim = Xs[i * 32 + 2 * k + 1];
            const float wrv = wr[(i * COUT_ + o) * MODES_ + k];
            const float wiv = wi[(i * COUT_ + o) * MODES_ + k];
            pr = fmaf(xre, wrv, fmaf(-xim, wiv, pr));
            pi = fmaf(xre, wiv, fmaf( xim, wrv, pi));
        }
        Ps[k][p][0] = pr;
        Ps[k][p][1] = pi;
    }
    __syncthreads();
    if (tid < 32) {
        const int k = tid & 15, comp = tid >> 4;
        float s = 0.f;
#pragma unroll
        for (int p = 0; p < 16; ++p) s += Ps[k][p][comp];
        const float g = (k == 0) ? (1.0f / RES_) : (2.0f / RES_);
        Csh[2 * k + comp] = g * s;
    }
    __syncthreads();

    float C[32];
#pragma unroll
    for (int q = 0; q < 8; ++q) {
        const float4 v = ((const float4*)Csh)[q];
        C[4 * q] = v.x; C[4 * q + 1] = v.y; C[4 * q + 2] = v.z; C[4 * q + 3] = v.w;
    }

    float* __restrict__ yr = y + (size_t)row * RES_;
    float yv[16][2];
#pragma unroll
    for (int half = 0; half < 2; ++half) {
        const int a = 2 * tid + half;
        float su, cu;
        __sincosf((float)a * W8192, &su, &cu);   // step e^{2pi i a/8192}
        float wre = 1.f, wim = 0.f;              // w = e^{2pi i k a/8192}, k=0
        float Er0 = 0.f, Er8 = 0.f, Er[8], Oi[8];
#pragma unroll
        for (int q = 1; q <= 7; ++q) { Er[q] = 0.f; Oi[q] = 0.f; }
#pragma unroll
        for (int k = 0; k < 16; ++k) {
            const float cre = C[2 * k], cim = C[2 * k + 1];
            const float dre = fmaf(cre, wre, -cim * wim);
            const float dim = fmaf(cre, wim,  cim * wre);
            if (k == 0)      { Er0 = dre; }
            else if (k == 8) { Er8 = dre; }
            else if (k < 8)  { Er[k]      += dre; Oi[k]      += dim; }
            else             { Er[16 - k] += dre; Oi[16 - k] -= dim; }
            const float nre = fmaf(wre, cu, -wim * su);
            wim = fmaf(wre, su, wim * cu);
            wre = nre;
        }
        // synthesis: y(bb) = Cc(bb) - Ss(bb), y(16-bb) = Cc(bb) + Ss(bb)
#pragma unroll
        for (int bb = 0; bb <= 8; ++bb) {
            float Cc = (bb & 1) ? (Er0 - Er8) : (Er0 + Er8);
            float Ss = 0.f;
#pragma unroll
            for (int q = 1; q <= 7; ++q) {
                Cc = fmaf(Er[q], COS16[(q * bb) & 15], Cc);
                Ss = fmaf(Oi[q], SIN16[(q * bb) & 15], Ss);
            }
            if (bb == 0)      yv[0][half] = Cc;      // Ss == 0
            else if (bb == 8) yv[8][half] = Cc;      // Ss == 0
            else { yv[bb][half] = Cc - Ss; yv[16 - bb][half] = Cc + Ss; }
        }
    }
#pragma unroll
    for (int bb = 0; bb < 16; ++bb)
        *(float2*)(yr + NA * bb + 2 * tid) = make_float2(yv[bb][0], yv[bb][1]);
}

extern "C" void kernel_launch(void* const* d_in, const int* in_sizes, int n_in,
                              void* d_out, int out_size, void* d_ws, size_t ws_size,
                              hipStream_t stream) {
    const float* x  = (const float*)d_in[0];
    const float* wr = (const float*)d_in[1];
    const float* wi = (const float*)d_in[2];
    float* out = (float*)d_out;
    float* X = (float*)d_ws;             // [4096][32] = 512 KB

    kA<<<dim3(B_ * CIN_), dim3(256), 0, stream>>>(x, X);
    kC<<<dim3(B_ * COUT_), dim3(256), 0, stream>>>(X, wr, wi, out);
}